// Round 9
// baseline (384.676 us; speedup 1.0000x reference)
//
#include <hip/hip_runtime.h>

#define N_NODES 100000
#define N_PAD 100352          // 392 * 256
#define NBLK 392
#define IN_FEAT 128
#define OUT_FEAT 128
#define NUM_RELS 64
#define EDGES_PER_REL 16384
#define NUM_BASES 16
#define E_TOTAL (NUM_RELS * EDGES_PER_REL)
#define TPB 4                 // 64-edge tiles per block in edge_gemm (256 edges)

typedef __bf16 bf16x8 __attribute__((ext_vector_type(8)));
typedef float floatx4 __attribute__((ext_vector_type(4)));

// ---------------------------------------------------------------------------
// Fused W composition (bf16 k-packed Wp[r][kp][n][j]) + loop_weight pack.
// ---------------------------------------------------------------------------
__global__ __launch_bounds__(256) void compose_all_bf16_kernel(
    const float* __restrict__ weight, const float* __restrict__ w_comp,
    const float* __restrict__ loop_w, __bf16* __restrict__ Wp,
    __bf16* __restrict__ Lp) {
  int gid = blockIdx.x * 256 + threadIdx.x;
  if (gid < NUM_RELS * 16384) {
    int r = gid >> 14;
    int off = gid & 16383;
    int j = off & 7, n = (off >> 3) & 127, kp = off >> 10;
    int k = kp * 8 + j;
    const float* wc = w_comp + r * NUM_BASES;
    float acc = 0.f;
#pragma unroll
    for (int b = 0; b < NUM_BASES; ++b)
      acc += wc[b] * weight[b * 16384 + k * 128 + n];
    Wp[gid] = (__bf16)acc;
  } else {
    int idx = gid - NUM_RELS * 16384;          // 16384 loop-weight elems
    int j = idx & 7, n = (idx >> 3) & 127, kp = idx >> 10;
    Lp[idx] = (__bf16)loop_w[(kp * 8 + j) * 128 + n];
  }
}

__global__ __launch_bounds__(256) void compose_w_f32_kernel(
    const float* __restrict__ weight, const float* __restrict__ w_comp,
    float* __restrict__ W) {
  int idx = blockIdx.x * 256 + threadIdx.x;
  int r = idx >> 14;
  int io = idx & 16383;
  const float* wc = w_comp + r * NUM_BASES;
  float acc = 0.f;
#pragma unroll
  for (int b = 0; b < NUM_BASES; ++b)
    acc += wc[b] * weight[b * 16384 + io];
  W[idx] = acc;
}

// ---------------------------------------------------------------------------
// out[n] = h_bias + feat[n] @ loop_weight   (MFMA bf16, 64 nodes / block)
// Also PRODUCES featb (bf16 feat copy) as a side output when non-null.
// ---------------------------------------------------------------------------
__global__ __launch_bounds__(256) void init_out_mfma(
    const float* __restrict__ feat, __bf16* __restrict__ featb,
    const __bf16* __restrict__ Lp, const float* __restrict__ bias,
    float* __restrict__ out) {
  __shared__ __bf16 A_lds[64 * 136];
  int t = threadIdx.x;
  long base = (long)blockIdx.x * 64;
#pragma unroll
  for (int j = 0; j < 8; ++j) {
    int idx = t + j * 256;
    int e = idx >> 5, k4 = idx & 31;
    long n = base + e;
    float4 v = make_float4(0.f, 0.f, 0.f, 0.f);
    bool ok = (n < N_NODES);
    if (ok) v = ((const float4*)feat)[n * 32 + k4];
    __bf16 tb[4] = {(__bf16)v.x, (__bf16)v.y, (__bf16)v.z, (__bf16)v.w};
    *(ushort4*)&A_lds[e * 136 + k4 * 4] = *(ushort4*)tb;
    if (featb && ok)
      *(ushort4*)(featb + n * 128 + k4 * 4) = *(ushort4*)tb;
  }
  __syncthreads();

  int wave = t >> 6, lane = t & 63;
  int m16 = lane & 15, quad = lane >> 4;
  floatx4 acc[8];
#pragma unroll
  for (int nt = 0; nt < 8; ++nt) acc[nt] = (floatx4){0.f, 0.f, 0.f, 0.f};

  const __bf16* a_base = &A_lds[(wave * 16 + m16) * 136 + quad * 8];
#pragma unroll
  for (int ks = 0; ks < 4; ++ks) {
    bf16x8 a = *(const bf16x8*)(a_base + ks * 32);
    int kp = ks * 4 + quad;
#pragma unroll
    for (int nt = 0; nt < 8; ++nt) {
      bf16x8 b = *(const bf16x8*)(Lp + (kp * 128 + nt * 16 + m16) * 8);
      acc[nt] = __builtin_amdgcn_mfma_f32_16x16x32_bf16(a, b, acc[nt], 0, 0, 0);
    }
  }

  float bv[8];
#pragma unroll
  for (int nt = 0; nt < 8; ++nt) bv[nt] = bias[nt * 16 + m16];
#pragma unroll
  for (int r = 0; r < 4; ++r) {
    long n = base + wave * 16 + quad * 4 + r;
    if (n < N_NODES) {
#pragma unroll
      for (int nt = 0; nt < 8; ++nt)
        out[n * 128 + nt * 16 + m16] = acc[nt][r] + bv[nt];
    }
  }
}

// ---------------------------------------------------------------------------
// Per-chunk CSR build: hist records each edge's arrival rank (atomicAdd
// return); after the scan, pos_fix finalizes IN-PLACE: rank[e] += row[dst[e]]
// -> rank becomes the absolute CSR slot (atomic-free sequential read in
// edge_gemm; round-7/8 comparison proved this worth ~8.5us/dispatch).
// ---------------------------------------------------------------------------
__global__ __launch_bounds__(256) void zero_kernel(int* __restrict__ p) {
  p[blockIdx.x * 256 + threadIdx.x] = 0;
}

__global__ __launch_bounds__(256) void hist_rank_kernel(
    const int* __restrict__ dst, int* __restrict__ cnt8,
    int* __restrict__ rank, int cshift) {
  int e = blockIdx.x * 256 + threadIdx.x;
  int c = e >> cshift;
  rank[e] = atomicAdd(&cnt8[c * N_PAD + dst[e]], 1);
}

__global__ __launch_bounds__(256) void scan1_kernel(
    const int* __restrict__ cnt, int* __restrict__ row,
    int* __restrict__ bsum) {
  __shared__ int s[256];
  int t = threadIdx.x;
  int idx = blockIdx.x * 256 + t;
  int v = cnt[idx];
  s[t] = v;
  __syncthreads();
  for (int o = 1; o < 256; o <<= 1) {
    int x = (t >= o) ? s[t - o] : 0;
    __syncthreads();
    s[t] += x;
    __syncthreads();
  }
  row[idx] = s[t] - v;
  if (t == 255) bsum[blockIdx.x] = s[t];
}

__global__ __launch_bounds__(512) void scan2_kernel(
    const int* __restrict__ bsum, int* __restrict__ boff) {
  __shared__ int s[512];
  int t = threadIdx.x;
  int v = (t < NBLK) ? bsum[blockIdx.x * NBLK + t] : 0;
  s[t] = v;
  __syncthreads();
  for (int o = 1; o < 512; o <<= 1) {
    int x = (t >= o) ? s[t - o] : 0;
    __syncthreads();
    s[t] += x;
    __syncthreads();
  }
  if (t < NBLK) boff[blockIdx.x * NBLK + t] = s[t] - v;
}

__global__ __launch_bounds__(256) void scan3_kernel(
    int* __restrict__ row, const int* __restrict__ boff) {
  int idx = blockIdx.x * 256 + threadIdx.x;
  row[idx] += boff[blockIdx.x];
}

// rank[e] += row[chunk(e)*N_PAD + dst[e]]  -> absolute CSR slot (in-place)
__global__ __launch_bounds__(256) void pos_fix_kernel(
    const int* __restrict__ dst, const int* __restrict__ row8,
    int* __restrict__ rank, int cshift) {
  int e = blockIdx.x * 256 + threadIdx.x;
  int c = e >> cshift;
  rank[e] += row8[(size_t)c * N_PAD + dst[e]];
}

// ---------------------------------------------------------------------------
// Phase A (MFMA): msg[pos[e]] = bf16((feat[src[e]] @ W[rel]) * norm[e])
// v9: D-bounce shrunk from a 64x136 block tile (17.4KB) to a per-wave 4-row
// strip (4x136 bf16 = 1.1KB/wave): epilogue bounces one r-group at a time
// (write 4 rows, wave_barrier, read/store 16B/lane, wave_barrier). LDS
// 50->37KB -> 4 blocks/CU (was 3), +33% resident waves for gather latency
// hiding (round-8: occupancy 24%, 54us vs 32us BW floor = latency-bound).
// Same total LDS op count; same HW-validated cross-lane bounce pattern.
// ---------------------------------------------------------------------------
__global__ __launch_bounds__(256) void edge_gemm_mfma(
    const float* __restrict__ feat, const __bf16* __restrict__ featb,
    const __bf16* __restrict__ Wp, const float* __restrict__ norm,
    const int* __restrict__ src, const int* __restrict__ pos,
    unsigned short* __restrict__ msg, int e_lo) {
  __shared__ __bf16 B_lds[IN_FEAT * OUT_FEAT];   // 32 KB, k-packed
  __shared__ __bf16 D_lds[4 * 4 * 136];          // 4.4 KB: 4 waves x 4-row strip
  int t = threadIdx.x;
  long base = (long)e_lo + (long)blockIdx.x * (64 * TPB);
  int rel = (int)(base >> 14);                   // 64*TPB divides 16384
  const __bf16* Wr = Wp + (long)rel * (IN_FEAT * OUT_FEAT);

  // stage B once per block (sequential, L2-hot across 64 blocks/rel)
  {
    const uint4* Wr4 = (const uint4*)Wr;
    uint4* B4 = (uint4*)B_lds;
#pragma unroll
    for (int j = 0; j < 8; ++j) B4[t + j * 256] = Wr4[t + j * 256];
  }

  int wave = t >> 6, lane = t & 63;
  int m16 = lane & 15, quad = lane >> 4;
  __bf16* Dw = &D_lds[wave * 544];               // this wave's 4x136 strip

  bf16x8 aA[4], aB[4];
  float nmA[4], nmB[4];
  int poA[4], poB[4];
  int srow0, srow1;

#define LOAD_SROW(dstv, it) (dstv) = src[base + (it) * 64 + wave * 16 + m16]

#define LOAD_TILE(aX, nmX, poX, it, srowX)                                   \
  do {                                                                       \
    if (featb) {                                                             \
      const __bf16* ap = featb + (long)(srowX)*128 + quad * 8;               \
      _Pragma("unroll") for (int ks = 0; ks < 4; ++ks)                       \
          aX[ks] = *(const bf16x8*)(ap + ks * 32);                           \
    } else {                                                                 \
      const float* fp = feat + (long)(srowX)*128 + quad * 8;                 \
      _Pragma("unroll") for (int ks = 0; ks < 4; ++ks) {                     \
        float4 lo = *(const float4*)(fp + ks * 32);                          \
        float4 hi = *(const float4*)(fp + ks * 32 + 4);                      \
        __bf16 tb[8] = {(__bf16)lo.x, (__bf16)lo.y, (__bf16)lo.z,            \
                        (__bf16)lo.w, (__bf16)hi.x, (__bf16)hi.y,            \
                        (__bf16)hi.z, (__bf16)hi.w};                         \
        aX[ks] = *(bf16x8*)tb;                                               \
      }                                                                      \
    }                                                                        \
    _Pragma("unroll") for (int r = 0; r < 4; ++r) {                          \
      nmX[r] = norm[base + (it) * 64 + wave * 16 + quad * 4 + r];            \
      poX[r] = pos[base + (it) * 64 + wave * 16 + quad * 4 + r];             \
    }                                                                        \
  } while (0)

#define COMPUTE_TILE(aX, nmX, poX)                                           \
  do {                                                                       \
    floatx4 acc[8];                                                          \
    _Pragma("unroll") for (int nt = 0; nt < 8; ++nt)                         \
        acc[nt] = (floatx4){0.f, 0.f, 0.f, 0.f};                             \
    _Pragma("unroll") for (int ks = 0; ks < 4; ++ks) {                       \
      int kp = ks * 4 + quad;                                                \
      _Pragma("unroll") for (int nt = 0; nt < 8; ++nt) {                     \
        bf16x8 b = *(const bf16x8*)(B_lds + (kp * 128 + nt * 16 + m16) * 8); \
        acc[nt] =                                                            \
            __builtin_amdgcn_mfma_f32_16x16x32_bf16(aX[ks], b, acc[nt],      \
                                                    0, 0, 0);                \
      }                                                                      \
    }                                                                        \
    /* r-group bounce: D[row=quad*4+r][col=nt*16+m16] -> slot[quad] */       \
    _Pragma("unroll") for (int r = 0; r < 4; ++r) {                          \
      _Pragma("unroll") for (int nt = 0; nt < 8; ++nt)                       \
          Dw[quad * 136 + nt * 16 + m16] = (__bf16)(acc[nt][r] * nmX[r]);    \
      __builtin_amdgcn_wave_barrier();                                       \
      uint4 v = *(const uint4*)&Dw[quad * 136 + m16 * 8];                    \
      *(uint4*)(msg + (long)poX[r] * 128 + m16 * 8) = v;                     \
      __builtin_amdgcn_wave_barrier();                                       \
    }                                                                        \
  } while (0)

  // -------- software pipeline: src 2 ahead, tile-data 1 ahead --------
  LOAD_SROW(srow0, 0);
  LOAD_SROW(srow1, 1);
  LOAD_TILE(aA, nmA, poA, 0, srow0);
  __syncthreads();  // B_lds ready

  LOAD_TILE(aB, nmB, poB, 1, srow1);
  LOAD_SROW(srow0, 2);
  COMPUTE_TILE(aA, nmA, poA);       // tile 0

  LOAD_TILE(aA, nmA, poA, 2, srow0);
  LOAD_SROW(srow1, 3);
  COMPUTE_TILE(aB, nmB, poB);       // tile 1

  LOAD_TILE(aB, nmB, poB, 3, srow1);
  COMPUTE_TILE(aA, nmA, poA);       // tile 2

  COMPUTE_TILE(aB, nmB, poB);       // tile 3

#undef LOAD_SROW
#undef LOAD_TILE
#undef COMPUTE_TILE
}

// ---------------------------------------------------------------------------
// Phase B: CSR gather, 4 msg rows / iter (uint4/lane = 1KB per wave-iter).
// ---------------------------------------------------------------------------
__global__ __launch_bounds__(256) void gather_csr_kernel(
    const unsigned short* __restrict__ msg, const int* __restrict__ rowc,
    float* __restrict__ out, int do_relu) {
  int wave = threadIdx.x >> 6, lane = threadIdx.x & 63;
  int n = blockIdx.x * 4 + wave;
  if (n >= N_NODES) return;
  int beg = rowc[n], end = rowc[n + 1];
  if (!do_relu && beg == end) return;
  int q = lane >> 4;
  int c8 = lane & 15;
  float s[8] = {0.f, 0.f, 0.f, 0.f, 0.f, 0.f, 0.f, 0.f};
  for (int j = beg; j < end; j += 4) {
    int jr = j + q;
    if (jr < end) {
      uint4 m = *(const uint4*)(msg + (long)jr * 128 + c8 * 8);
      s[0] += __uint_as_float(m.x << 16);
      s[1] += __uint_as_float(m.x & 0xFFFF0000u);
      s[2] += __uint_as_float(m.y << 16);
      s[3] += __uint_as_float(m.y & 0xFFFF0000u);
      s[4] += __uint_as_float(m.z << 16);
      s[5] += __uint_as_float(m.z & 0xFFFF0000u);
      s[6] += __uint_as_float(m.w << 16);
      s[7] += __uint_as_float(m.w & 0xFFFF0000u);
    }
  }
#pragma unroll
  for (int k = 0; k < 8; ++k) {
    s[k] += __shfl_xor(s[k], 16);
    s[k] += __shfl_xor(s[k], 32);
  }
  if (q == 0) {
    float4 o0 = ((float4*)out)[(long)n * 32 + c8 * 2];
    float4 o1 = ((float4*)out)[(long)n * 32 + c8 * 2 + 1];
    o0.x += s[0]; o0.y += s[1]; o0.z += s[2]; o0.w += s[3];
    o1.x += s[4]; o1.y += s[5]; o1.z += s[6]; o1.w += s[7];
    if (do_relu) {
      o0.x = fmaxf(o0.x, 0.f); o0.y = fmaxf(o0.y, 0.f);
      o0.z = fmaxf(o0.z, 0.f); o0.w = fmaxf(o0.w, 0.f);
      o1.x = fmaxf(o1.x, 0.f); o1.y = fmaxf(o1.y, 0.f);
      o1.z = fmaxf(o1.z, 0.f); o1.w = fmaxf(o1.w, 0.f);
    }
    ((float4*)out)[(long)n * 32 + c8 * 2] = o0;
    ((float4*)out)[(long)n * 32 + c8 * 2 + 1] = o1;
  }
}

// ---------------------------------------------------------------------------
// Fallback (tiny ws): fp32 init + GEMM + atomic scatter + relu
// ---------------------------------------------------------------------------
__global__ __launch_bounds__(256) void init_out_f32_kernel(
    const float* __restrict__ feat, const float* __restrict__ loop_w,
    const float* __restrict__ bias, float* __restrict__ out) {
  __shared__ float4 A4[64][32];
  int t = threadIdx.x;
  long base = (long)blockIdx.x * 64;
#pragma unroll
  for (int j = 0; j < 8; ++j) {
    int idx = t + j * 256;
    int e = idx >> 5, k4 = idx & 31;
    long n = base + e;
    float4 v = make_float4(0.f, 0.f, 0.f, 0.f);
    if (n < N_NODES) v = ((const float4*)feat)[n * 32 + k4];
    A4[e][k4] = v;
  }
  __syncthreads();
  int og = t & 31, eg = t >> 5;
  float acc[8][4];
#pragma unroll
  for (int j = 0; j < 8; ++j)
#pragma unroll
    for (int d = 0; d < 4; ++d) acc[j][d] = 0.f;
  const float4* W4 = (const float4*)loop_w;
  for (int k4 = 0; k4 < 32; ++k4) {
    float4 a[8];
#pragma unroll
    for (int j = 0; j < 8; ++j) a[j] = A4[eg * 8 + j][k4];
#pragma unroll
    for (int d = 0; d < 4; ++d) {
      float4 w = W4[(k4 * 4 + d) * 32 + og];
#pragma unroll
      for (int j = 0; j < 8; ++j) {
        float av = ((const float*)&a[j])[d];
        acc[j][0] += av * w.x;
        acc[j][1] += av * w.y;
        acc[j][2] += av * w.z;
        acc[j][3] += av * w.w;
      }
    }
  }
  float4 b = ((const float4*)bias)[og];
#pragma unroll
  for (int j = 0; j < 8; ++j) {
    long n = base + eg * 8 + j;
    if (n < N_NODES) {
      float4 v = make_float4(acc[j][0] + b.x, acc[j][1] + b.y,
                             acc[j][2] + b.z, acc[j][3] + b.w);
      ((float4*)out)[n * 32 + og] = v;
    }
  }
}

__global__ __launch_bounds__(256) void edge_msg_atomic_kernel(
    const float* __restrict__ feat, const float* __restrict__ W,
    const float* __restrict__ norm, const int* __restrict__ src,
    const int* __restrict__ dst, float* __restrict__ out) {
  __shared__ float4 A4[64][32];
  __shared__ int s_src[64];
  __shared__ int s_dst[64];
  __shared__ float s_norm[64];
  int t = threadIdx.x;
  long base = (long)blockIdx.x * 64;
  int rel = blockIdx.x >> 8;
  const float4* Wr4 = (const float4*)(W + (long)rel * IN_FEAT * OUT_FEAT);
  if (t < 64) {
    s_src[t] = src[base + t];
    s_dst[t] = dst[base + t];
    s_norm[t] = norm[base + t];
  }
  __syncthreads();
#pragma unroll
  for (int j = 0; j < 8; ++j) {
    int idx = t + j * 256;
    int e = idx >> 5, k4 = idx & 31;
    A4[e][k4] = ((const float4*)feat)[(long)s_src[e] * 32 + k4];
  }
  __syncthreads();
  int og = t & 31, eg = t >> 5;
  float acc[8][4];
#pragma unroll
  for (int j = 0; j < 8; ++j)
#pragma unroll
    for (int d = 0; d < 4; ++d) acc[j][d] = 0.f;
  for (int k4 = 0; k4 < 32; ++k4) {
    float4 a[8];
#pragma unroll
    for (int j = 0; j < 8; ++j) a[j] = A4[eg * 8 + j][k4];
#pragma unroll
    for (int d = 0; d < 4; ++d) {
      float4 w = Wr4[(k4 * 4 + d) * 32 + og];
#pragma unroll
      for (int j = 0; j < 8; ++j) {
        float av = ((const float*)&a[j])[d];
        acc[j][0] += av * w.x;
        acc[j][1] += av * w.y;
        acc[j][2] += av * w.z;
        acc[j][3] += av * w.w;
      }
    }
  }
#pragma unroll
  for (int j = 0; j < 8; ++j) {
    int e = eg * 8 + j;
    float nm = s_norm[e];
    float* orow = out + (long)s_dst[e] * OUT_FEAT + og * 4;
#pragma unroll
    for (int d = 0; d < 4; ++d) atomicAdd(orow + d, acc[j][d] * nm);
  }
}

__global__ __launch_bounds__(256) void relu_kernel(float* __restrict__ out) {
  int idx = blockIdx.x * 256 + threadIdx.x;
  float4 v = ((const float4*)out)[idx];
  v.x = fmaxf(v.x, 0.f);
  v.y = fmaxf(v.y, 0.f);
  v.z = fmaxf(v.z, 0.f);
  v.w = fmaxf(v.w, 0.f);
  ((float4*)out)[idx] = v;
}

extern "C" void kernel_launch(void* const* d_in, const int* in_sizes, int n_in,
                              void* d_out, int out_size, void* d_ws, size_t ws_size,
                              hipStream_t stream) {
  const float* feat   = (const float*)d_in[0];
  const float* weight = (const float*)d_in[1];
  const float* w_comp = (const float*)d_in[2];
  const float* h_bias = (const float*)d_in[3];
  const float* loop_w = (const float*)d_in[4];
  const float* norm   = (const float*)d_in[5];
  const int*   src    = (const int*)d_in[6];
  const int*   dst    = (const int*)d_in[7];
  float* out = (float*)d_out;

  const size_t SZ_WP   = (size_t)NUM_RELS * IN_FEAT * OUT_FEAT * 2;  // 2 MB
  const size_t SZ_LP   = (size_t)IN_FEAT * OUT_FEAT * 2;             // 32 KB
  const size_t SZ_FB   = (size_t)N_NODES * IN_FEAT * 2;              // 25.6 MB
  const size_t SZ_RANK = (size_t)E_TOTAL * 4;                        // 4 MB

  // Config ladder: fewest out-RMW passes first, then the bf16-feat copy.
  int CH = 0, FB = 0;
  {
    const int chs[11] = {64, 64, 32, 32, 16, 16, 8, 8, 4, 4, 0};
    const int fbs[11] = { 1,  0,  1,  0,  1,  0, 1, 0, 1, 0, 0};
    for (int i = 0; i < 10 && CH == 0; ++i) {
      int ch = chs[i], fb = fbs[i], nc = NUM_RELS / ch;
      size_t need = SZ_WP + SZ_LP + (fb ? SZ_FB : 0) + SZ_RANK +
                    2 * (size_t)nc * N_PAD * 4 + 2 * (size_t)nc * NBLK * 4 +
                    (size_t)ch * EDGES_PER_REL * OUT_FEAT * 2;
      if (ws_size >= need) { CH = ch; FB = fb; }
    }
  }

  if (CH > 0) {
    const int NC = NUM_RELS / CH;
    const int chunk_edges = CH * EDGES_PER_REL;
    int cshift = 14;
    for (int x = CH; x > 1; x >>= 1) ++cshift;

    char* p = (char*)d_ws;
    __bf16* Wp = (__bf16*)p;                  p += SZ_WP;
    __bf16* Lp = (__bf16*)p;                  p += SZ_LP;
    __bf16* featb = nullptr;
    if (FB) { featb = (__bf16*)p;             p += SZ_FB; }
    int* rank = (int*)p;                      p += SZ_RANK;
    int* cnt8 = (int*)p;                      p += (size_t)NC * N_PAD * 4;
    int* row8 = (int*)p;                      p += (size_t)NC * N_PAD * 4;
    int* bsum = (int*)p;                      p += (size_t)NC * NBLK * 4;
    int* boff = (int*)p;                      p += (size_t)NC * NBLK * 4;
    unsigned short* msg = (unsigned short*)p;

    hipLaunchKernelGGL(compose_all_bf16_kernel,
                       dim3((NUM_RELS * 16384 + 16384) / 256), dim3(256), 0,
                       stream, weight, w_comp, loop_w, Wp, Lp);
    hipLaunchKernelGGL(init_out_mfma, dim3((N_NODES + 63) / 64), dim3(256), 0,
                       stream, feat, featb, Lp, h_bias, out);
    hipLaunchKernelGGL(zero_kernel, dim3(NC * NBLK), dim3(256), 0, stream, cnt8);
    hipLaunchKernelGGL(hist_rank_kernel, dim3(E_TOTAL / 256), dim3(256), 0,
                       stream, dst, cnt8, rank, cshift);
    hipLaunchKernelGGL(scan1_kernel, dim3(NC * NBLK), dim3(256), 0, stream,
                       cnt8, row8, bsum);
    hipLaunchKernelGGL(scan2_kernel, dim3(NC), dim3(512), 0, stream, bsum, boff);
    hipLaunchKernelGGL(scan3_kernel, dim3(NC * NBLK), dim3(256), 0, stream,
                       row8, boff);
    hipLaunchKernelGGL(pos_fix_kernel, dim3(E_TOTAL / 256), dim3(256), 0,
                       stream, dst, row8, rank, cshift);

    for (int c = 0; c < NC; ++c) {
      hipLaunchKernelGGL(edge_gemm_mfma, dim3(chunk_edges / (64 * TPB)),
                         dim3(256), 0, stream, feat, featb, Wp, norm, src,
                         rank, msg, c * chunk_edges);
      hipLaunchKernelGGL(gather_csr_kernel, dim3((N_NODES + 3) / 4), dim3(256),
                         0, stream, msg, row8 + (size_t)c * N_PAD, out,
                         (c == NC - 1) ? 1 : 0);
    }
  } else {
    float* W = (float*)d_ws;
    hipLaunchKernelGGL(init_out_f32_kernel, dim3((N_NODES + 63) / 64),
                       dim3(256), 0, stream, feat, loop_w, h_bias, out);
    hipLaunchKernelGGL(compose_w_f32_kernel, dim3(NUM_RELS * 16384 / 256),
                       dim3(256), 0, stream, weight, w_comp, W);
    hipLaunchKernelGGL(edge_msg_atomic_kernel, dim3(E_TOTAL / 64), dim3(256), 0,
                       stream, feat, W, norm, src, dst, out);
    hipLaunchKernelGGL(relu_kernel, dim3((N_NODES * OUT_FEAT / 4) / 256),
                       dim3(256), 0, stream, out);
  }
}

// Round 10
// 379.686 us; speedup vs baseline: 1.0131x; 1.0131x over previous
//
#include <hip/hip_runtime.h>

#define N_NODES 100000
#define N_PAD 100352          // 392 * 256
#define NBLK 392
#define IN_FEAT 128
#define OUT_FEAT 128
#define NUM_RELS 64
#define EDGES_PER_REL 16384
#define NUM_BASES 16
#define E_TOTAL (NUM_RELS * EDGES_PER_REL)
#define TPB 4                 // 64-edge tiles per block in edge_gemm (256 edges)
#define W_WORK (NUM_RELS * 16384)
#define L_WORK 16384
#define F_WORK (N_NODES * IN_FEAT / 8)   // 1.6M: featb pack, 8 elems/thread

typedef __bf16 bf16x8 __attribute__((ext_vector_type(8)));
typedef float floatx4 __attribute__((ext_vector_type(4)));

// ---------------------------------------------------------------------------
// Fused prep: W composition (bf16 k-packed Wp), loop_weight pack (Lp), and
// featb = bf16(feat) streaming copy (v10: moved here from init_out).
// ---------------------------------------------------------------------------
__global__ __launch_bounds__(256) void compose_all_bf16_kernel(
    const float* __restrict__ weight, const float* __restrict__ w_comp,
    const float* __restrict__ loop_w, const float* __restrict__ feat,
    __bf16* __restrict__ Wp, __bf16* __restrict__ Lp,
    __bf16* __restrict__ featb) {
  int gid = blockIdx.x * 256 + threadIdx.x;
  if (gid < W_WORK) {
    int r = gid >> 14;
    int off = gid & 16383;
    int j = off & 7, n = (off >> 3) & 127, kp = off >> 10;
    int k = kp * 8 + j;
    const float* wc = w_comp + r * NUM_BASES;
    float acc = 0.f;
#pragma unroll
    for (int b = 0; b < NUM_BASES; ++b)
      acc += wc[b] * weight[b * 16384 + k * 128 + n];
    Wp[gid] = (__bf16)acc;
  } else if (gid < W_WORK + L_WORK) {
    int idx = gid - W_WORK;
    int j = idx & 7, n = (idx >> 3) & 127, kp = idx >> 10;
    Lp[idx] = (__bf16)loop_w[(kp * 8 + j) * 128 + n];
  } else {
    if (!featb) return;
    long i = (long)(gid - W_WORK - L_WORK) * 8;
    float4 a = *(const float4*)(feat + i);
    float4 b = *(const float4*)(feat + i + 4);
    __bf16 t8[8] = {(__bf16)a.x, (__bf16)a.y, (__bf16)a.z, (__bf16)a.w,
                    (__bf16)b.x, (__bf16)b.y, (__bf16)b.z, (__bf16)b.w};
    *(uint4*)(featb + i) = *(uint4*)t8;
  }
}

__global__ __launch_bounds__(256) void compose_w_f32_kernel(
    const float* __restrict__ weight, const float* __restrict__ w_comp,
    float* __restrict__ W) {
  int idx = blockIdx.x * 256 + threadIdx.x;
  int r = idx >> 14;
  int io = idx & 16383;
  const float* wc = w_comp + r * NUM_BASES;
  float acc = 0.f;
#pragma unroll
  for (int b = 0; b < NUM_BASES; ++b)
    acc += wc[b] * weight[b * 16384 + io];
  W[idx] = acc;
}

// ---------------------------------------------------------------------------
// v10 FINAL pass: out = relu(out + h_bias + featb[n] @ loop_weight).
// Runs AFTER the gathers (gather c=0 now writes out directly, saving its
// RMW read). A-fragments straight from featb (26MB, not 51MB feat) into
// registers — no LDS at all. B from Lp (32KB, L2-hot).
// ---------------------------------------------------------------------------
__global__ __launch_bounds__(256) void finish_out_mfma(
    const float* __restrict__ feat, const __bf16* __restrict__ featb,
    const __bf16* __restrict__ Lp, const float* __restrict__ bias,
    float* __restrict__ out) {
  int t = threadIdx.x;
  long base = (long)blockIdx.x * 64;
  int wave = t >> 6, lane = t & 63;
  int m16 = lane & 15, quad = lane >> 4;

  long n_a = base + wave * 16 + m16;
  long n_c = (n_a < N_NODES) ? n_a : (N_NODES - 1);   // clamp; guarded on store
  bf16x8 a[4];
  if (featb) {
    const __bf16* ap = featb + n_c * 128 + quad * 8;
#pragma unroll
    for (int ks = 0; ks < 4; ++ks) a[ks] = *(const bf16x8*)(ap + ks * 32);
  } else {
    const float* fp = feat + n_c * 128 + quad * 8;
#pragma unroll
    for (int ks = 0; ks < 4; ++ks) {
      float4 lo = *(const float4*)(fp + ks * 32);
      float4 hi = *(const float4*)(fp + ks * 32 + 4);
      __bf16 tb[8] = {(__bf16)lo.x, (__bf16)lo.y, (__bf16)lo.z, (__bf16)lo.w,
                      (__bf16)hi.x, (__bf16)hi.y, (__bf16)hi.z, (__bf16)hi.w};
      a[ks] = *(bf16x8*)tb;
    }
  }

  floatx4 acc[8];
#pragma unroll
  for (int nt = 0; nt < 8; ++nt) acc[nt] = (floatx4){0.f, 0.f, 0.f, 0.f};
#pragma unroll
  for (int ks = 0; ks < 4; ++ks) {
    int kp = ks * 4 + quad;
#pragma unroll
    for (int nt = 0; nt < 8; ++nt) {
      bf16x8 b = *(const bf16x8*)(Lp + (kp * 128 + nt * 16 + m16) * 8);
      acc[nt] = __builtin_amdgcn_mfma_f32_16x16x32_bf16(a[ks], b, acc[nt], 0, 0, 0);
    }
  }

  float bv[8];
#pragma unroll
  for (int nt = 0; nt < 8; ++nt) bv[nt] = bias[nt * 16 + m16];
#pragma unroll
  for (int r = 0; r < 4; ++r) {
    long n = base + wave * 16 + quad * 4 + r;
    if (n < N_NODES) {
#pragma unroll
      for (int nt = 0; nt < 8; ++nt) {
        float o = out[n * 128 + nt * 16 + m16] + acc[nt][r] + bv[nt];
        out[n * 128 + nt * 16 + m16] = fmaxf(o, 0.f);
      }
    }
  }
}

// ---------------------------------------------------------------------------
// Per-chunk CSR build: hist records each edge's arrival rank (atomicAdd
// return); after the scan, pos_fix finalizes IN-PLACE: rank[e] += row[dst[e]]
// -> rank becomes the absolute CSR slot (atomic-free sequential read in
// edge_gemm; round-7/8 comparison proved this worth ~8.5us/dispatch).
// ---------------------------------------------------------------------------
__global__ __launch_bounds__(256) void zero_kernel(int* __restrict__ p) {
  p[blockIdx.x * 256 + threadIdx.x] = 0;
}

__global__ __launch_bounds__(256) void hist_rank_kernel(
    const int* __restrict__ dst, int* __restrict__ cnt8,
    int* __restrict__ rank, int cshift) {
  int e = blockIdx.x * 256 + threadIdx.x;
  int c = e >> cshift;
  rank[e] = atomicAdd(&cnt8[c * N_PAD + dst[e]], 1);
}

__global__ __launch_bounds__(256) void scan1_kernel(
    const int* __restrict__ cnt, int* __restrict__ row,
    int* __restrict__ bsum) {
  __shared__ int s[256];
  int t = threadIdx.x;
  int idx = blockIdx.x * 256 + t;
  int v = cnt[idx];
  s[t] = v;
  __syncthreads();
  for (int o = 1; o < 256; o <<= 1) {
    int x = (t >= o) ? s[t - o] : 0;
    __syncthreads();
    s[t] += x;
    __syncthreads();
  }
  row[idx] = s[t] - v;
  if (t == 255) bsum[blockIdx.x] = s[t];
}

__global__ __launch_bounds__(512) void scan2_kernel(
    const int* __restrict__ bsum, int* __restrict__ boff) {
  __shared__ int s[512];
  int t = threadIdx.x;
  int v = (t < NBLK) ? bsum[blockIdx.x * NBLK + t] : 0;
  s[t] = v;
  __syncthreads();
  for (int o = 1; o < 512; o <<= 1) {
    int x = (t >= o) ? s[t - o] : 0;
    __syncthreads();
    s[t] += x;
    __syncthreads();
  }
  if (t < NBLK) boff[blockIdx.x * NBLK + t] = s[t] - v;
}

__global__ __launch_bounds__(256) void scan3_kernel(
    int* __restrict__ row, const int* __restrict__ boff) {
  int idx = blockIdx.x * 256 + threadIdx.x;
  row[idx] += boff[blockIdx.x];
}

// rank[e] += row[chunk(e)*N_PAD + dst[e]]  -> absolute CSR slot (in-place)
__global__ __launch_bounds__(256) void pos_fix_kernel(
    const int* __restrict__ dst, const int* __restrict__ row8,
    int* __restrict__ rank, int cshift) {
  int e = blockIdx.x * 256 + threadIdx.x;
  int c = e >> cshift;
  rank[e] += row8[(size_t)c * N_PAD + dst[e]];
}

// ---------------------------------------------------------------------------
// Phase A (MFMA): msg[pos[e]] = bf16((feat[src[e]] @ W[rel]) * norm[e])
// v10: D-strip row stride 136->144 elems (288B -> quad bank offset 8):
// the 4 quads' write rows now map to disjoint bank groups (0-7/8-15/16-23/
// 24-31), killing the 2.6M bank-conflict cycles v9 introduced. LDS ~37KB,
// 4 blocks/CU. Occupancy lift in v9 proved Phase A is random-gather
// memory-system-bound (occ +33% -> dur -1%), so this is the last cheap win.
// ---------------------------------------------------------------------------
__global__ __launch_bounds__(256) void edge_gemm_mfma(
    const float* __restrict__ feat, const __bf16* __restrict__ featb,
    const __bf16* __restrict__ Wp, const float* __restrict__ norm,
    const int* __restrict__ src, const int* __restrict__ pos,
    unsigned short* __restrict__ msg, int e_lo) {
  __shared__ __bf16 B_lds[IN_FEAT * OUT_FEAT];   // 32 KB, k-packed
  __shared__ __bf16 D_lds[4 * 4 * 144];          // 4.6 KB: 4 waves x 4x144 strip
  int t = threadIdx.x;
  long base = (long)e_lo + (long)blockIdx.x * (64 * TPB);
  int rel = (int)(base >> 14);                   // 64*TPB divides 16384
  const __bf16* Wr = Wp + (long)rel * (IN_FEAT * OUT_FEAT);

  // stage B once per block (sequential, L2-hot across 64 blocks/rel)
  {
    const uint4* Wr4 = (const uint4*)Wr;
    uint4* B4 = (uint4*)B_lds;
#pragma unroll
    for (int j = 0; j < 8; ++j) B4[t + j * 256] = Wr4[t + j * 256];
  }

  int wave = t >> 6, lane = t & 63;
  int m16 = lane & 15, quad = lane >> 4;
  __bf16* Dw = &D_lds[wave * 576];               // this wave's 4x144 strip

  bf16x8 aA[4], aB[4];
  float nmA[4], nmB[4];
  int poA[4], poB[4];
  int srow0, srow1;

#define LOAD_SROW(dstv, it) (dstv) = src[base + (it) * 64 + wave * 16 + m16]

#define LOAD_TILE(aX, nmX, poX, it, srowX)                                   \
  do {                                                                       \
    if (featb) {                                                             \
      const __bf16* ap = featb + (long)(srowX)*128 + quad * 8;               \
      _Pragma("unroll") for (int ks = 0; ks < 4; ++ks)                       \
          aX[ks] = *(const bf16x8*)(ap + ks * 32);                           \
    } else {                                                                 \
      const float* fp = feat + (long)(srowX)*128 + quad * 8;                 \
      _Pragma("unroll") for (int ks = 0; ks < 4; ++ks) {                     \
        float4 lo = *(const float4*)(fp + ks * 32);                          \
        float4 hi = *(const float4*)(fp + ks * 32 + 4);                      \
        __bf16 tb[8] = {(__bf16)lo.x, (__bf16)lo.y, (__bf16)lo.z,            \
                        (__bf16)lo.w, (__bf16)hi.x, (__bf16)hi.y,            \
                        (__bf16)hi.z, (__bf16)hi.w};                         \
        aX[ks] = *(bf16x8*)tb;                                               \
      }                                                                      \
    }                                                                        \
    _Pragma("unroll") for (int r = 0; r < 4; ++r) {                          \
      nmX[r] = norm[base + (it) * 64 + wave * 16 + quad * 4 + r];            \
      poX[r] = pos[base + (it) * 64 + wave * 16 + quad * 4 + r];             \
    }                                                                        \
  } while (0)

#define COMPUTE_TILE(aX, nmX, poX)                                           \
  do {                                                                       \
    floatx4 acc[8];                                                          \
    _Pragma("unroll") for (int nt = 0; nt < 8; ++nt)                         \
        acc[nt] = (floatx4){0.f, 0.f, 0.f, 0.f};                             \
    _Pragma("unroll") for (int ks = 0; ks < 4; ++ks) {                       \
      int kp = ks * 4 + quad;                                                \
      _Pragma("unroll") for (int nt = 0; nt < 8; ++nt) {                     \
        bf16x8 b = *(const bf16x8*)(B_lds + (kp * 128 + nt * 16 + m16) * 8); \
        acc[nt] =                                                            \
            __builtin_amdgcn_mfma_f32_16x16x32_bf16(aX[ks], b, acc[nt],      \
                                                    0, 0, 0);                \
      }                                                                      \
    }                                                                        \
    /* r-group bounce: D[row=quad*4+r][col=nt*16+m16] -> slot[quad] */       \
    _Pragma("unroll") for (int r = 0; r < 4; ++r) {                          \
      _Pragma("unroll") for (int nt = 0; nt < 8; ++nt)                       \
          Dw[quad * 144 + nt * 16 + m16] = (__bf16)(acc[nt][r] * nmX[r]);    \
      __builtin_amdgcn_wave_barrier();                                       \
      uint4 v = *(const uint4*)&Dw[quad * 144 + m16 * 8];                    \
      *(uint4*)(msg + (long)poX[r] * 128 + m16 * 8) = v;                     \
      __builtin_amdgcn_wave_barrier();                                       \
    }                                                                        \
  } while (0)

  // -------- software pipeline: src 2 ahead, tile-data 1 ahead --------
  LOAD_SROW(srow0, 0);
  LOAD_SROW(srow1, 1);
  LOAD_TILE(aA, nmA, poA, 0, srow0);
  __syncthreads();  // B_lds ready

  LOAD_TILE(aB, nmB, poB, 1, srow1);
  LOAD_SROW(srow0, 2);
  COMPUTE_TILE(aA, nmA, poA);       // tile 0

  LOAD_TILE(aA, nmA, poA, 2, srow0);
  LOAD_SROW(srow1, 3);
  COMPUTE_TILE(aB, nmB, poB);       // tile 1

  LOAD_TILE(aB, nmB, poB, 3, srow1);
  COMPUTE_TILE(aA, nmA, poA);       // tile 2

  COMPUTE_TILE(aB, nmB, poB);       // tile 3

#undef LOAD_SROW
#undef LOAD_TILE
#undef COMPUTE_TILE
}

// ---------------------------------------------------------------------------
// Phase B: CSR gather, 4 msg rows / iter (uint4/lane = 1KB per wave-iter).
// v10: write_mode (chunk 0) writes out = sums for ALL nodes (zeros for
// empty) with NO out read; later chunks RMW-add (skip empty). ReLU moved
// to finish_out_mfma.
// ---------------------------------------------------------------------------
__global__ __launch_bounds__(256) void gather_csr_kernel(
    const unsigned short* __restrict__ msg, const int* __restrict__ rowc,
    float* __restrict__ out, int write_mode) {
  int wave = threadIdx.x >> 6, lane = threadIdx.x & 63;
  int n = blockIdx.x * 4 + wave;
  if (n >= N_NODES) return;
  int beg = rowc[n], end = rowc[n + 1];
  if (!write_mode && beg == end) return;
  int q = lane >> 4;
  int c8 = lane & 15;
  float s[8] = {0.f, 0.f, 0.f, 0.f, 0.f, 0.f, 0.f, 0.f};
  for (int j = beg; j < end; j += 4) {
    int jr = j + q;
    if (jr < end) {
      uint4 m = *(const uint4*)(msg + (long)jr * 128 + c8 * 8);
      s[0] += __uint_as_float(m.x << 16);
      s[1] += __uint_as_float(m.x & 0xFFFF0000u);
      s[2] += __uint_as_float(m.y << 16);
      s[3] += __uint_as_float(m.y & 0xFFFF0000u);
      s[4] += __uint_as_float(m.z << 16);
      s[5] += __uint_as_float(m.z & 0xFFFF0000u);
      s[6] += __uint_as_float(m.w << 16);
      s[7] += __uint_as_float(m.w & 0xFFFF0000u);
    }
  }
#pragma unroll
  for (int k = 0; k < 8; ++k) {
    s[k] += __shfl_xor(s[k], 16);
    s[k] += __shfl_xor(s[k], 32);
  }
  if (q == 0) {
    if (write_mode) {
      ((float4*)out)[(long)n * 32 + c8 * 2] =
          make_float4(s[0], s[1], s[2], s[3]);
      ((float4*)out)[(long)n * 32 + c8 * 2 + 1] =
          make_float4(s[4], s[5], s[6], s[7]);
    } else {
      float4 o0 = ((float4*)out)[(long)n * 32 + c8 * 2];
      float4 o1 = ((float4*)out)[(long)n * 32 + c8 * 2 + 1];
      o0.x += s[0]; o0.y += s[1]; o0.z += s[2]; o0.w += s[3];
      o1.x += s[4]; o1.y += s[5]; o1.z += s[6]; o1.w += s[7];
      ((float4*)out)[(long)n * 32 + c8 * 2] = o0;
      ((float4*)out)[(long)n * 32 + c8 * 2 + 1] = o1;
    }
  }
}

// ---------------------------------------------------------------------------
// Fallback (tiny ws): fp32 init + GEMM + atomic scatter + relu
// ---------------------------------------------------------------------------
__global__ __launch_bounds__(256) void init_out_f32_kernel(
    const float* __restrict__ feat, const float* __restrict__ loop_w,
    const float* __restrict__ bias, float* __restrict__ out) {
  __shared__ float4 A4[64][32];
  int t = threadIdx.x;
  long base = (long)blockIdx.x * 64;
#pragma unroll
  for (int j = 0; j < 8; ++j) {
    int idx = t + j * 256;
    int e = idx >> 5, k4 = idx & 31;
    long n = base + e;
    float4 v = make_float4(0.f, 0.f, 0.f, 0.f);
    if (n < N_NODES) v = ((const float4*)feat)[n * 32 + k4];
    A4[e][k4] = v;
  }
  __syncthreads();
  int og = t & 31, eg = t >> 5;
  float acc[8][4];
#pragma unroll
  for (int j = 0; j < 8; ++j)
#pragma unroll
    for (int d = 0; d < 4; ++d) acc[j][d] = 0.f;
  const float4* W4 = (const float4*)loop_w;
  for (int k4 = 0; k4 < 32; ++k4) {
    float4 a[8];
#pragma unroll
    for (int j = 0; j < 8; ++j) a[j] = A4[eg * 8 + j][k4];
#pragma unroll
    for (int d = 0; d < 4; ++d) {
      float4 w = W4[(k4 * 4 + d) * 32 + og];
#pragma unroll
      for (int j = 0; j < 8; ++j) {
        float av = ((const float*)&a[j])[d];
        acc[j][0] += av * w.x;
        acc[j][1] += av * w.y;
        acc[j][2] += av * w.z;
        acc[j][3] += av * w.w;
      }
    }
  }
  float4 b = ((const float4*)bias)[og];
#pragma unroll
  for (int j = 0; j < 8; ++j) {
    long n = base + eg * 8 + j;
    if (n < N_NODES) {
      float4 v = make_float4(acc[j][0] + b.x, acc[j][1] + b.y,
                             acc[j][2] + b.z, acc[j][3] + b.w);
      ((float4*)out)[n * 32 + og] = v;
    }
  }
}

__global__ __launch_bounds__(256) void edge_msg_atomic_kernel(
    const float* __restrict__ feat, const float* __restrict__ W,
    const float* __restrict__ norm, const int* __restrict__ src,
    const int* __restrict__ dst, float* __restrict__ out) {
  __shared__ float4 A4[64][32];
  __shared__ int s_src[64];
  __shared__ int s_dst[64];
  __shared__ float s_norm[64];
  int t = threadIdx.x;
  long base = (long)blockIdx.x * 64;
  int rel = blockIdx.x >> 8;
  const float4* Wr4 = (const float4*)(W + (long)rel * IN_FEAT * OUT_FEAT);
  if (t < 64) {
    s_src[t] = src[base + t];
    s_dst[t] = dst[base + t];
    s_norm[t] = norm[base + t];
  }
  __syncthreads();
#pragma unroll
  for (int j = 0; j < 8; ++j) {
    int idx = t + j * 256;
    int e = idx >> 5, k4 = idx & 31;
    A4[e][k4] = ((const float4*)feat)[(long)s_src[e] * 32 + k4];
  }
  __syncthreads();
  int og = t & 31, eg = t >> 5;
  float acc[8][4];
#pragma unroll
  for (int j = 0; j < 8; ++j)
#pragma unroll
    for (int d = 0; d < 4; ++d) acc[j][d] = 0.f;
  for (int k4 = 0; k4 < 32; ++k4) {
    float4 a[8];
#pragma unroll
    for (int j = 0; j < 8; ++j) a[j] = A4[eg * 8 + j][k4];
#pragma unroll
    for (int d = 0; d < 4; ++d) {
      float4 w = Wr4[(k4 * 4 + d) * 32 + og];
#pragma unroll
      for (int j = 0; j < 8; ++j) {
        float av = ((const float*)&a[j])[d];
        acc[j][0] += av * w.x;
        acc[j][1] += av * w.y;
        acc[j][2] += av * w.z;
        acc[j][3] += av * w.w;
      }
    }
  }
#pragma unroll
  for (int j = 0; j < 8; ++j) {
    int e = eg * 8 + j;
    float nm = s_norm[e];
    float* orow = out + (long)s_dst[e] * OUT_FEAT + og * 4;
#pragma unroll
    for (int d = 0; d < 4; ++d) atomicAdd(orow + d, acc[j][d] * nm);
  }
}

__global__ __launch_bounds__(256) void relu_kernel(float* __restrict__ out) {
  int idx = blockIdx.x * 256 + threadIdx.x;
  float4 v = ((const float4*)out)[idx];
  v.x = fmaxf(v.x, 0.f);
  v.y = fmaxf(v.y, 0.f);
  v.z = fmaxf(v.z, 0.f);
  v.w = fmaxf(v.w, 0.f);
  ((float4*)out)[idx] = v;
}

extern "C" void kernel_launch(void* const* d_in, const int* in_sizes, int n_in,
                              void* d_out, int out_size, void* d_ws, size_t ws_size,
                              hipStream_t stream) {
  const float* feat   = (const float*)d_in[0];
  const float* weight = (const float*)d_in[1];
  const float* w_comp = (const float*)d_in[2];
  const float* h_bias = (const float*)d_in[3];
  const float* loop_w = (const float*)d_in[4];
  const float* norm   = (const float*)d_in[5];
  const int*   src    = (const int*)d_in[6];
  const int*   dst    = (const int*)d_in[7];
  float* out = (float*)d_out;

  const size_t SZ_WP   = (size_t)NUM_RELS * IN_FEAT * OUT_FEAT * 2;  // 2 MB
  const size_t SZ_LP   = (size_t)IN_FEAT * OUT_FEAT * 2;             // 32 KB
  const size_t SZ_FB   = (size_t)N_NODES * IN_FEAT * 2;              // 25.6 MB
  const size_t SZ_RANK = (size_t)E_TOTAL * 4;                        // 4 MB

  // Config ladder: fewest out-RMW passes first, then the bf16-feat copy.
  int CH = 0, FB = 0;
  {
    const int chs[11] = {64, 64, 32, 32, 16, 16, 8, 8, 4, 4, 0};
    const int fbs[11] = { 1,  0,  1,  0,  1,  0, 1, 0, 1, 0, 0};
    for (int i = 0; i < 10 && CH == 0; ++i) {
      int ch = chs[i], fb = fbs[i], nc = NUM_RELS / ch;
      size_t need = SZ_WP + SZ_LP + (fb ? SZ_FB : 0) + SZ_RANK +
                    2 * (size_t)nc * N_PAD * 4 + 2 * (size_t)nc * NBLK * 4 +
                    (size_t)ch * EDGES_PER_REL * OUT_FEAT * 2;
      if (ws_size >= need) { CH = ch; FB = fb; }
    }
  }

  if (CH > 0) {
    const int NC = NUM_RELS / CH;
    const int chunk_edges = CH * EDGES_PER_REL;
    int cshift = 14;
    for (int x = CH; x > 1; x >>= 1) ++cshift;

    char* p = (char*)d_ws;
    __bf16* Wp = (__bf16*)p;                  p += SZ_WP;
    __bf16* Lp = (__bf16*)p;                  p += SZ_LP;
    __bf16* featb = nullptr;
    if (FB) { featb = (__bf16*)p;             p += SZ_FB; }
    int* rank = (int*)p;                      p += SZ_RANK;
    int* cnt8 = (int*)p;                      p += (size_t)NC * N_PAD * 4;
    int* row8 = (int*)p;                      p += (size_t)NC * N_PAD * 4;
    int* bsum = (int*)p;                      p += (size_t)NC * NBLK * 4;
    int* boff = (int*)p;                      p += (size_t)NC * NBLK * 4;
    unsigned short* msg = (unsigned short*)p;

    hipLaunchKernelGGL(compose_all_bf16_kernel,
                       dim3((W_WORK + L_WORK + F_WORK) / 256), dim3(256), 0,
                       stream, weight, w_comp, loop_w, feat, Wp, Lp, featb);
    hipLaunchKernelGGL(zero_kernel, dim3(NC * NBLK), dim3(256), 0, stream, cnt8);
    hipLaunchKernelGGL(hist_rank_kernel, dim3(E_TOTAL / 256), dim3(256), 0,
                       stream, dst, cnt8, rank, cshift);
    hipLaunchKernelGGL(scan1_kernel, dim3(NC * NBLK), dim3(256), 0, stream,
                       cnt8, row8, bsum);
    hipLaunchKernelGGL(scan2_kernel, dim3(NC), dim3(512), 0, stream, bsum, boff);
    hipLaunchKernelGGL(scan3_kernel, dim3(NC * NBLK), dim3(256), 0, stream,
                       row8, boff);
    hipLaunchKernelGGL(pos_fix_kernel, dim3(E_TOTAL / 256), dim3(256), 0,
                       stream, dst, row8, rank, cshift);

    for (int c = 0; c < NC; ++c) {
      hipLaunchKernelGGL(edge_gemm_mfma, dim3(chunk_edges / (64 * TPB)),
                         dim3(256), 0, stream, feat, featb, Wp, norm, src,
                         rank, msg, c * chunk_edges);
      hipLaunchKernelGGL(gather_csr_kernel, dim3((N_NODES + 3) / 4), dim3(256),
                         0, stream, msg, row8 + (size_t)c * N_PAD, out,
                         (c == 0) ? 1 : 0);
    }
    hipLaunchKernelGGL(finish_out_mfma, dim3((N_NODES + 63) / 64), dim3(256),
                       0, stream, feat, featb, Lp, h_bias, out);
  } else {
    float* W = (float*)d_ws;
    hipLaunchKernelGGL(init_out_f32_kernel, dim3((N_NODES + 63) / 64),
                       dim3(256), 0, stream, feat, loop_w, h_bias, out);
    hipLaunchKernelGGL(compose_w_f32_kernel, dim3(NUM_RELS * 16384 / 256),
                       dim3(256), 0, stream, weight, w_comp, W);
    hipLaunchKernelGGL(edge_msg_atomic_kernel, dim3(E_TOTAL / 64), dim3(256), 0,
                       stream, feat, W, norm, src, dst, out);
    hipLaunchKernelGGL(relu_kernel, dim3((N_NODES * OUT_FEAT / 4) / 256),
                       dim3(256), 0, stream, out);
  }
}